// Round 7
// baseline (8789.588 us; speedup 1.0000x reference)
//
#include <hip/hip_runtime.h>
#include <math.h>

// Problem constants
#define B_ 256
#define S_ 128
#define F_ 128
#define H_ 512
#define A_ 512
#define C_ 128

#define DOT4(va, vb) ((va).x*(vb).x + (va).y*(vb).y + (va).z*(vb).z + (va).w*(vb).w)

// ---------------------------------------------------------------------------
// xT[t][f][b] = x[b][t][f]
// ---------------------------------------------------------------------------
__global__ __launch_bounds__(256)
void transpose_x(const float* __restrict__ x, float* __restrict__ xT)
{
    const int t = blockIdx.x >> 2;
    const int f0 = (blockIdx.x & 3) * 32;
    const int b = threadIdx.x;
#pragma unroll 4
    for (int ff = 0; ff < 32; ++ff) {
        int f = f0 + ff;
        xT[(size_t)t * (F_ * B_) + (size_t)f * B_ + b] =
            x[(size_t)b * (S_ * F_) + (size_t)t * F_ + f];
    }
}

// ---------------------------------------------------------------------------
// W6[up][k][6]: up owns units u0=2up,u0+1. g: r(u0),r(u1),z(u0),z(u1),n(u0),n(u1)
// k<128 -> Wih (K=F), k>=128 -> Whh (K=H)
// ---------------------------------------------------------------------------
__global__ __launch_bounds__(256)
void prep_w6(const float* __restrict__ Wih, const float* __restrict__ Whh,
             float* __restrict__ W6)
{
    int id = blockIdx.x * 256 + threadIdx.x;
    if (id >= 256 * 640 * 6) return;
    int up = id / 3840;
    int rem = id - up * 3840;
    int k = rem / 6, g = rem - k * 6;
    int row = (g >> 1) * H_ + up * 2 + (g & 1);
    float val;
    if (k < F_) val = Wih[(size_t)row * F_ + k];
    else        val = Whh[(size_t)row * H_ + (k - F_)];
    W6[id] = val;
}

// w2q[k4][a] = float4{ w2[a][4k4 .. 4k4+3] }; also zero dec_inT
__global__ __launch_bounds__(256)
void prep_w2q(const float* __restrict__ w2, float4* __restrict__ w2q,
              float* __restrict__ dec_inT)
{
    int id = blockIdx.x * 256 + threadIdx.x;
    if (id < 128 * 512) {
        int k4 = id >> 9, a = id & 511;
        const float* s = w2 + (size_t)a * H_ + k4 * 4;
        w2q[id] = make_float4(s[0], s[1], s[2], s[3]);
    }
    if (id < F_ * B_) dec_inT[id] = 0.f;
}

// bias4[u] = {br, bz, bin, bhn}; zero h0T; zero flags
__global__ __launch_bounds__(256)
void prep_bias(const float* __restrict__ ebih, const float* __restrict__ ebhh,
               const float* __restrict__ dbih, const float* __restrict__ dbhh,
               float* __restrict__ bias4e, float* __restrict__ bias4d,
               float* __restrict__ h0T, int* __restrict__ flags)
{
    int id = blockIdx.x * 256 + threadIdx.x;
    if (id < H_ * B_) h0T[id] = 0.f;
    if (id < S_) flags[id] = 0;
    if (id < H_) {
        bias4e[id * 4 + 0] = ebih[id] + ebhh[id];
        bias4e[id * 4 + 1] = ebih[H_ + id] + ebhh[H_ + id];
        bias4e[id * 4 + 2] = ebih[2 * H_ + id];
        bias4e[id * 4 + 3] = ebhh[2 * H_ + id];
        bias4d[id * 4 + 0] = dbih[id] + dbhh[id];
        bias4d[id * 4 + 1] = dbih[H_ + id] + dbhh[H_ + id];
        bias4d[id * 4 + 2] = dbih[2 * H_ + id];
        bias4d[id * 4 + 3] = dbhh[2 * H_ + id];
    }
}

// ---------------------------------------------------------------------------
// accumulate nk k-values from k-major src into acc[0..3] and acc[NH],acc[NH+1]
// ---------------------------------------------------------------------------
template<int NH>
__device__ __forceinline__ void acc_range(const float* __restrict__ src,
                                          const float* __restrict__ W6k,
                                          int nk, int b, float* __restrict__ acc)
{
    float a0[8], a1[8];
#pragma unroll
    for (int j = 0; j < 8; ++j) a0[j] = src[(size_t)j * B_ + b];
    for (int kc = 0; kc < nk; kc += 8) {
        if (kc + 8 < nk) {
#pragma unroll
            for (int j = 0; j < 8; ++j) a1[j] = src[(size_t)(kc + 8 + j) * B_ + b];
        }
        const float* Wr = W6k + (size_t)kc * 6;
#pragma unroll
        for (int j = 0; j < 8; ++j) {
            float av = a0[j];
            acc[0]      = fmaf(av, Wr[j * 6 + 0], acc[0]);
            acc[1]      = fmaf(av, Wr[j * 6 + 1], acc[1]);
            acc[2]      = fmaf(av, Wr[j * 6 + 2], acc[2]);
            acc[3]      = fmaf(av, Wr[j * 6 + 3], acc[3]);
            acc[NH]     = fmaf(av, Wr[j * 6 + 4], acc[NH]);
            acc[NH + 1] = fmaf(av, Wr[j * 6 + 5], acc[NH + 1]);
        }
#pragma unroll
        for (int j = 0; j < 8; ++j) a0[j] = a1[j];
    }
}

// ---------------------------------------------------------------------------
// PERSISTENT encoder: 256 blocks (unit-pair each), 512 threads (kw x bg waves).
// Per step t: h-exchange via device-scope relaxed-atomic (sc1) stores into the
// virgin slice encT[t]; per-step flag = count of finished blocks; readers use
// normal cached loads (virgin addresses within this kernel; deterministic
// values across graph replays).
// ---------------------------------------------------------------------------
__global__ __launch_bounds__(512)
void enc_persist(const float* __restrict__ xT,     // [S][F][B]
                 const float* __restrict__ W6,     // [256][640][6]
                 const float* __restrict__ bias4,  // [512][4]
                 const float* __restrict__ h0T,    // [H][B] zeros
                 float* __restrict__ encT,         // [S][H][B]
                 int* __restrict__ flags)          // [S]
{
    __shared__ float accL[256][6];
    const int tid = threadIdx.x;
    const int lane = tid & 63;
    const int w = tid >> 6;
    const int bg = w & 3;
    const int kw = w >> 2;
    const int b = bg * 64 + lane;
    const int up = blockIdx.x;
    const float* Wb = W6 + (size_t)up * (640 * 6);
    const int u0 = up * 2, u1 = u0 + 1;
    const float4 bb0 = *(const float4*)(bias4 + u0 * 4);
    const float4 bb1 = *(const float4*)(bias4 + u1 * 4);

    for (int t = 0; t < S_; ++t) {
        const float* inT = xT + (size_t)t * (F_ * B_);
        const float* hinT = (t == 0) ? h0T : encT + (size_t)(t - 1) * (H_ * B_);
        float* houtT = encT + (size_t)t * (H_ * B_);

        float acc[8];
#pragma unroll
        for (int g = 0; g < 8; ++g) acc[g] = 0.f;

        // x-part first (independent of h) to hide the flag wait
        if (kw == 0) acc_range<4>(inT, Wb, F_, b, acc);

        // wait for previous step's h to be fully published
        if (t > 0) {
            if (tid == 0) {
                while (__hip_atomic_load(&flags[t - 1], __ATOMIC_RELAXED,
                                         __HIP_MEMORY_SCOPE_AGENT) != 256) {
                    __builtin_amdgcn_s_sleep(1);
                }
            }
        }
        __syncthreads();   // releases block; also compiler/memory barrier

        if (kw == 0) {
            acc_range<6>(hinT, Wb + F_ * 6, 192, b, acc);
        } else {
            acc_range<6>(hinT + (size_t)192 * B_, Wb + 320 * 6, 320, b, acc);
        }

        if (kw == 1) {
            const int li = tid & 255;
            accL[li][0] = acc[0]; accL[li][1] = acc[1];
            accL[li][2] = acc[2]; accL[li][3] = acc[3];
            accL[li][4] = acc[6]; accL[li][5] = acc[7];
        }
        __syncthreads();
        if (kw == 0) {
            float rr0 = 1.f / (1.f + expf(-(acc[0] + accL[tid][0] + bb0.x)));
            float rr1 = 1.f / (1.f + expf(-(acc[1] + accL[tid][1] + bb1.x)));
            float zz0 = 1.f / (1.f + expf(-(acc[2] + accL[tid][2] + bb0.y)));
            float zz1 = 1.f / (1.f + expf(-(acc[3] + accL[tid][3] + bb1.y)));
            float hn0 = acc[6] + accL[tid][4] + bb0.w;
            float hn1 = acc[7] + accL[tid][5] + bb1.w;
            float nn0 = tanhf(acc[4] + bb0.z + rr0 * hn0);
            float nn1 = tanhf(acc[5] + bb1.z + rr1 * hn1);
            float ho0 = hinT[(size_t)u0 * B_ + b];
            float ho1 = hinT[(size_t)u1 * B_ + b];
            float h0v = (1.f - zz0) * nn0 + zz0 * ho0;
            float h1v = (1.f - zz1) * nn1 + zz1 * ho1;
            // publish via device-coherent (sc1) stores
            __hip_atomic_store(&houtT[(size_t)u0 * B_ + b], h0v,
                               __ATOMIC_RELAXED, __HIP_MEMORY_SCOPE_AGENT);
            __hip_atomic_store(&houtT[(size_t)u1 * B_ + b], h1v,
                               __ATOMIC_RELAXED, __HIP_MEMORY_SCOPE_AGENT);
        }
        // ensure this thread's stores reached the coherent point
        asm volatile("s_waitcnt vmcnt(0)" ::: "memory");
        __syncthreads();
        if (tid == 0) {
            __hip_atomic_fetch_add(&flags[t], 1, __ATOMIC_RELAXED,
                                   __HIP_MEMORY_SCOPE_AGENT);
        }
    }
}

// ---------------------------------------------------------------------------
// Decoder GRU step (unchanged from round 6). Writes hT and b-major hB.
// ---------------------------------------------------------------------------
__global__ __launch_bounds__(512)
void gru_step(const float* __restrict__ inT,    // [F_][B_] (k-major)
              const float* __restrict__ hinT,   // [H_][B_]
              const float* __restrict__ W6,     // [256][640][6]
              const float* __restrict__ bias4,  // [512][4]
              float* __restrict__ houtT,        // [H_][B_]
              float* __restrict__ hB)           // [B_][H_] or nullptr
{
    __shared__ float accL[256][6];
    const int tid = threadIdx.x;
    const int lane = tid & 63;
    const int w = tid >> 6;
    const int bg = w & 3;
    const int kw = w >> 2;
    const int b = bg * 64 + lane;
    const int up = blockIdx.x;
    const float* Wb = W6 + (size_t)up * (640 * 6);

    float acc[8];
#pragma unroll
    for (int g = 0; g < 8; ++g) acc[g] = 0.f;

    if (kw == 0) {
        acc_range<4>(inT, Wb, F_, b, acc);
        acc_range<6>(hinT, Wb + F_ * 6, 192, b, acc);
    } else {
        acc_range<6>(hinT + (size_t)192 * B_, Wb + 320 * 6, 320, b, acc);
    }

    if (kw == 1) {
        const int li = tid & 255;
        accL[li][0] = acc[0]; accL[li][1] = acc[1];
        accL[li][2] = acc[2]; accL[li][3] = acc[3];
        accL[li][4] = acc[6]; accL[li][5] = acc[7];
    }
    __syncthreads();
    if (kw == 0) {
        const int u0 = up * 2, u1 = u0 + 1;
        float4 bb0 = *(const float4*)(bias4 + u0 * 4);
        float4 bb1 = *(const float4*)(bias4 + u1 * 4);
        float rr0 = 1.f / (1.f + expf(-(acc[0] + accL[tid][0] + bb0.x)));
        float rr1 = 1.f / (1.f + expf(-(acc[1] + accL[tid][1] + bb1.x)));
        float zz0 = 1.f / (1.f + expf(-(acc[2] + accL[tid][2] + bb0.y)));
        float zz1 = 1.f / (1.f + expf(-(acc[3] + accL[tid][3] + bb1.y)));
        float hn0 = acc[6] + accL[tid][4] + bb0.w;
        float hn1 = acc[7] + accL[tid][5] + bb1.w;
        float nn0 = tanhf(acc[4] + bb0.z + rr0 * hn0);
        float nn1 = tanhf(acc[5] + bb1.z + rr1 * hn1);
        float ho0 = hinT[(size_t)u0 * B_ + b];
        float ho1 = hinT[(size_t)u1 * B_ + b];
        float h0v = (1.f - zz0) * nn0 + zz0 * ho0;
        float h1v = (1.f - zz1) * nn1 + zz1 * ho1;
        houtT[(size_t)u0 * B_ + b] = h0v;
        houtT[(size_t)u1 * B_ + b] = h1v;
        if (hB) {
            hB[(size_t)b * H_ + u0] = h0v;
            hB[(size_t)b * H_ + u1] = h1v;
        }
    }
}

// ---------------------------------------------------------------------------
// Fused w2 + attention + softmax + argmax + loss + gather (round 6, unchanged)
// ---------------------------------------------------------------------------
__global__ __launch_bounds__(512)
void w2attn_step(const float* __restrict__ hB,    // [B_][H_]
                 const float4* __restrict__ w2q,  // [128 k4][512 a]
                 const float* __restrict__ v, const int* __restrict__ y,
                 int step, const float* __restrict__ x,
                 const float* __restrict__ proj,  // [b][s][a]
                 float* __restrict__ dec_inT,     // [F_][B_]
                 float* __restrict__ nlogp, float* __restrict__ preds_out)
{
    const int b = blockIdx.x;
    const int tid = threadIdx.x;
    __shared__ float sh[512];
    __shared__ float sq[512];
    __shared__ float sScore[S_], sProb[S_];
    __shared__ int sPred;

    sh[tid] = hB[(size_t)b * H_ + tid];
    __syncthreads();

    {
        float acc = 0.f;
        const float4* wp = w2q + tid;
#pragma unroll 8
        for (int k4 = 0; k4 < 128; ++k4) {
            float4 hv = *(const float4*)&sh[k4 * 4];
            float4 wv4 = wp[(size_t)k4 * 512];
            acc += DOT4(hv, wv4);
        }
        sq[tid] = acc;
    }
    __syncthreads();

    const int wv = tid >> 6, ln = tid & 63;
    float4 q0 = *(const float4*)&sq[ln * 8];
    float4 q1 = *(const float4*)&sq[ln * 8 + 4];
    float4 v0r = *(const float4*)(v + ln * 8);
    float4 v1r = *(const float4*)(v + ln * 8 + 4);
    const float* epb = proj + (size_t)b * (S_ * A_);
    for (int si = 0; si < 16; ++si) {
        int s = si * 8 + wv;
        const float* row = epb + (size_t)s * A_ + ln * 8;
        float4 p0 = *(const float4*)(row);
        float4 p1 = *(const float4*)(row + 4);
        float acc = fmaxf(p0.x + q0.x, 0.f) * v0r.x
                  + fmaxf(p0.y + q0.y, 0.f) * v0r.y
                  + fmaxf(p0.z + q0.z, 0.f) * v0r.z
                  + fmaxf(p0.w + q0.w, 0.f) * v0r.w
                  + fmaxf(p1.x + q1.x, 0.f) * v1r.x
                  + fmaxf(p1.y + q1.y, 0.f) * v1r.y
                  + fmaxf(p1.z + q1.z, 0.f) * v1r.z
                  + fmaxf(p1.w + q1.w, 0.f) * v1r.w;
#pragma unroll
        for (int off = 32; off; off >>= 1) acc += __shfl_down(acc, off);
        if (ln == 0) sScore[s] = acc;
    }
    __syncthreads();

    if (tid < 64) {
        float s0v = sScore[tid], s1v = sScore[tid + 64];
        float m = fmaxf(s0v, s1v);
#pragma unroll
        for (int off = 32; off; off >>= 1) m = fmaxf(m, __shfl_xor(m, off));
        float e0 = expf(s0v - m), e1 = expf(s1v - m);
        float se = e0 + e1;
#pragma unroll
        for (int off = 32; off; off >>= 1) se += __shfl_xor(se, off);
        float p0 = e0 / se, p1 = e1 / se;
        sProb[tid] = p0; sProb[tid + 64] = p1;
        float pm = fmaxf(p0, p1);
#pragma unroll
        for (int off = 32; off; off >>= 1) pm = fmaxf(pm, __shfl_xor(pm, off));
        float t0 = expf(p0 - pm), t1 = expf(p1 - pm);
        float T = t0 + t1;
#pragma unroll
        for (int off = 32; off; off >>= 1) T += __shfl_xor(T, off);
        float bv = p0; int bi2 = tid;
        if (p1 > bv) { bv = p1; bi2 = tid + 64; }
#pragma unroll
        for (int off = 32; off; off >>= 1) {
            float ov = __shfl_xor(bv, off);
            int oi = __shfl_xor(bi2, off);
            if (ov > bv || (ov == bv && oi < bi2)) { bv = ov; bi2 = oi; }
        }
        if (tid == 0) {
            sPred = bi2;
            int yy = y[(size_t)b * C_ + step];
            float py = sProb[yy];
            nlogp[(size_t)step * B_ + b] = -(py - pm - logf(T));
            preds_out[(size_t)b * C_ + step] = (float)bi2;
        }
    }
    __syncthreads();

    const int pred = sPred;
    if (tid < F_) {
        dec_inT[(size_t)tid * B_ + b] = x[((size_t)b * S_ + pred) * F_ + tid];
    }
}

// ---------------------------------------------------------------------------
// proj[b][s][a] = sum_j encT[s][j][b] * w1[a][j]   (TN GEMM, 128x128 tiles)
// ---------------------------------------------------------------------------
__global__ __launch_bounds__(256)
void proj_gemm(const float* __restrict__ encT, const float* __restrict__ w1,
               float* __restrict__ proj)
{
    __shared__ float sA[32][128];
    __shared__ float sB[32][128];
    const int tid = threadIdx.x;
    const int s = blockIdx.z;
    const int b0 = blockIdx.y * 128;
    const int a0 = blockIdx.x * 128;
    const int tx = tid & 15, ty = tid >> 4;

    float acc[8][8];
#pragma unroll
    for (int i = 0; i < 8; ++i)
#pragma unroll
        for (int j = 0; j < 8; ++j) acc[i][j] = 0.f;

    const float* Abase = encT + (size_t)s * (H_ * B_) + b0;
    for (int kc = 0; kc < H_; kc += 32) {
#pragma unroll
        for (int p = 0; p < 16; ++p) {
            int idx = tid + p * 256;
            int kj = idx >> 7, bb = idx & 127;
            sA[kj][bb] = Abase[(size_t)(kc + kj) * B_ + bb];
        }
#pragma unroll
        for (int p = 0; p < 16; ++p) {
            int idx = tid + p * 256;
            int aa = idx >> 5, kj = idx & 31;
            sB[kj][aa] = w1[(size_t)(a0 + aa) * H_ + kc + kj];
        }
        __syncthreads();
#pragma unroll
        for (int kj = 0; kj < 32; ++kj) {
            float4 af0 = *(const float4*)&sA[kj][ty * 8];
            float4 af1 = *(const float4*)&sA[kj][ty * 8 + 4];
            float4 bf0 = *(const float4*)&sB[kj][tx * 8];
            float4 bf1 = *(const float4*)&sB[kj][tx * 8 + 4];
            float am[8] = {af0.x, af0.y, af0.z, af0.w, af1.x, af1.y, af1.z, af1.w};
            float bn[8] = {bf0.x, bf0.y, bf0.z, bf0.w, bf1.x, bf1.y, bf1.z, bf1.w};
#pragma unroll
            for (int i = 0; i < 8; ++i)
#pragma unroll
                for (int j = 0; j < 8; ++j)
                    acc[i][j] = fmaf(am[i], bn[j], acc[i][j]);
        }
        __syncthreads();
    }
#pragma unroll
    for (int i = 0; i < 8; ++i) {
        float* dst = proj + ((size_t)(b0 + ty * 8 + i) * S_ + s) * A_ + a0 + tx * 8;
        *(float4*)(dst) = make_float4(acc[i][0], acc[i][1], acc[i][2], acc[i][3]);
        *(float4*)(dst + 4) = make_float4(acc[i][4], acc[i][5], acc[i][6], acc[i][7]);
    }
}

__global__ void final_loss(const float* __restrict__ nlogp, float* __restrict__ out)
{
    __shared__ float part[C_];
    const int i = threadIdx.x; // 128
    float s = 0.f;
    for (int b = 0; b < B_; ++b) s += nlogp[(size_t)i * B_ + b];
    part[i] = s / (float)B_;
    __syncthreads();
    if (i == 0) {
        float t = 0.f;
        for (int k = 0; k < C_; ++k) t += part[k];
        out[0] = t / (float)B_ / (float)C_;
    }
}

extern "C" void kernel_launch(void* const* d_in, const int* in_sizes, int n_in,
                              void* d_out, int out_size, void* d_ws, size_t ws_size,
                              hipStream_t stream)
{
    (void)in_sizes; (void)n_in; (void)out_size; (void)ws_size;
    const float* x    = (const float*)d_in[0];
    const int*   y    = (const int*)d_in[1];
    const float* eWih = (const float*)d_in[2];
    const float* eWhh = (const float*)d_in[3];
    const float* ebih = (const float*)d_in[4];
    const float* ebhh = (const float*)d_in[5];
    const float* dWih = (const float*)d_in[6];
    const float* dWhh = (const float*)d_in[7];
    const float* dbih = (const float*)d_in[8];
    const float* dbhh = (const float*)d_in[9];
    const float* w1   = (const float*)d_in[10];
    const float* w2   = (const float*)d_in[11];
    const float* v    = (const float*)d_in[12];
    float* out = (float*)d_out;

    float* ws = (float*)d_ws;
    // Region A: encT [128][512][256] = 16,777,216 floats.
    float* encT    = ws;
    float* W6d     = ws;                    // 983,040 (dead encT slices t<8)
    float* w2qf    = ws + 983040;           // 262,144
    float* hT0     = ws + 1245184;          // 131,072
    float* hT1     = ws + 1376256;          // 131,072
    float* dec_inT = ws + 1507328;          // 32,768
    float* nlogp   = ws + 1540096;          // 32,768
    float* hB      = ws + 1572864;          // 131,072
    float* encT127 = ws + 16646144;         // encoder final h (stays live)
    // Region B: proj. Before proj written: xT, W6e, h0T.
    float* projB   = ws + 16777216;
    float* xT      = projB;                 // 4,194,304
    float* W6e     = projB + 4194304;       // 983,040
    float* h0T     = projB + 5177344;       // 131,072
    // Region C
    float* bias4e  = ws + 33554432;
    float* bias4d  = ws + 33554432 + 2048;
    int*   flags   = (int*)(ws + 33554432 + 4096);   // [128]

    // ---- prep ----
    prep_bias<<<dim3(512), 256, 0, stream>>>(ebih, ebhh, dbih, dbhh,
                                             bias4e, bias4d, h0T, flags);
    transpose_x<<<dim3(512), 256, 0, stream>>>(x, xT);
    prep_w6<<<dim3(3840), 256, 0, stream>>>(eWih, eWhh, W6e);

    // ---- encoder: ONE persistent cooperative kernel, 128 steps ----
    {
        void* a[] = { (void*)&xT, (void*)&W6e, (void*)&bias4e, (void*)&h0T,
                      (void*)&encT, (void*)&flags };
        hipLaunchCooperativeKernel((const void*)enc_persist,
                                   dim3(256), dim3(512), a, 0, stream);
    }

    // ---- proj ----
    proj_gemm<<<dim3(4, 2, 128), 256, 0, stream>>>(encT, w1, projB);

    // ---- decoder prep (into dead encT slices; after proj_gemm read encT) ----
    prep_w6<<<dim3(3840), 256, 0, stream>>>(dWih, dWhh, W6d);
    prep_w2q<<<dim3(256), 256, 0, stream>>>(w2, (float4*)w2qf, dec_inT);

    // ---- decoder: 128 steps x 2 kernels ----
    float* hb[2] = { hT0, hT1 };
    for (int i = 0; i < C_; ++i) {
        const float* hin = (i == 0) ? encT127 : hb[(i & 1) ^ 1];
        float* hout = hb[i & 1];
        gru_step<<<dim3(256), 512, 0, stream>>>(dec_inT, hin, W6d, bias4d,
                                                hout, hB);
        w2attn_step<<<dim3(256), 512, 0, stream>>>(hB, (const float4*)w2qf, v, y,
                                                   i, x, projB, dec_inT,
                                                   nlogp, out);
    }

    final_loss<<<dim3(1), 128, 0, stream>>>(nlogp, out + (size_t)B_ * C_);
}

// Round 8
// 8785.087 us; speedup vs baseline: 1.0005x; 1.0005x over previous
//
#include <hip/hip_runtime.h>
#include <math.h>

// Problem constants
#define B_ 256
#define S_ 128
#define F_ 128
#define H_ 512
#define A_ 512
#define C_ 128

#define DOT4(va, vb) ((va).x*(vb).x + (va).y*(vb).y + (va).z*(vb).z + (va).w*(vb).w)

// ---------------------------------------------------------------------------
// xT[t][f][b] = x[b][t][f]
// ---------------------------------------------------------------------------
__global__ __launch_bounds__(256)
void transpose_x(const float* __restrict__ x, float* __restrict__ xT)
{
    const int t = blockIdx.x >> 2;
    const int f0 = (blockIdx.x & 3) * 32;
    const int b = threadIdx.x;
#pragma unroll 4
    for (int ff = 0; ff < 32; ++ff) {
        int f = f0 + ff;
        xT[(size_t)t * (F_ * B_) + (size_t)f * B_ + b] =
            x[(size_t)b * (S_ * F_) + (size_t)t * F_ + f];
    }
}

// ---------------------------------------------------------------------------
// W6[up][k][6]: up owns units u0=2up,u0+1. g: r(u0),r(u1),z(u0),z(u1),n(u0),n(u1)
// ---------------------------------------------------------------------------
__global__ __launch_bounds__(256)
void prep_w6(const float* __restrict__ Wih, const float* __restrict__ Whh,
             float* __restrict__ W6)
{
    int id = blockIdx.x * 256 + threadIdx.x;
    if (id >= 256 * 640 * 6) return;
    int up = id / 3840;
    int rem = id - up * 3840;
    int k = rem / 6, g = rem - k * 6;
    int row = (g >> 1) * H_ + up * 2 + (g & 1);
    float val;
    if (k < F_) val = Wih[(size_t)row * F_ + k];
    else        val = Whh[(size_t)row * H_ + (k - F_)];
    W6[id] = val;
}

// w2q[k4][a] = float4{ w2[a][4k4 .. 4k4+3] }; also zero dec_inT
__global__ __launch_bounds__(256)
void prep_w2q(const float* __restrict__ w2, float4* __restrict__ w2q,
              float* __restrict__ dec_inT)
{
    int id = blockIdx.x * 256 + threadIdx.x;
    if (id < 128 * 512) {
        int k4 = id >> 9, a = id & 511;
        const float* s = w2 + (size_t)a * H_ + k4 * 4;
        w2q[id] = make_float4(s[0], s[1], s[2], s[3]);
    }
    if (id < F_ * B_) dec_inT[id] = 0.f;
}

// bias4[u] = {br, bz, bin, bhn}; zero h0T; zero both flag arrays
__global__ __launch_bounds__(256)
void prep_bias(const float* __restrict__ ebih, const float* __restrict__ ebhh,
               const float* __restrict__ dbih, const float* __restrict__ dbhh,
               float* __restrict__ bias4e, float* __restrict__ bias4d,
               float* __restrict__ h0T, int* __restrict__ eflags,
               int* __restrict__ dflags)
{
    int id = blockIdx.x * 256 + threadIdx.x;
    if (id < H_ * B_) h0T[id] = 0.f;
    if (id < 256 * 32) { eflags[id] = 0; dflags[id] = 0; }
    if (id < H_) {
        bias4e[id * 4 + 0] = ebih[id] + ebhh[id];
        bias4e[id * 4 + 1] = ebih[H_ + id] + ebhh[H_ + id];
        bias4e[id * 4 + 2] = ebih[2 * H_ + id];
        bias4e[id * 4 + 3] = ebhh[2 * H_ + id];
        bias4d[id * 4 + 0] = dbih[id] + dbhh[id];
        bias4d[id * 4 + 1] = dbih[H_ + id] + dbhh[H_ + id];
        bias4d[id * 4 + 2] = dbih[2 * H_ + id];
        bias4d[id * 4 + 3] = dbhh[2 * H_ + id];
    }
}

// ---------------------------------------------------------------------------
// accumulate nk k-values from k-major src into acc[0..3] and acc[NH],acc[NH+1]
// ---------------------------------------------------------------------------
template<int NH>
__device__ __forceinline__ void acc_range(const float* __restrict__ src,
                                          const float* __restrict__ W6k,
                                          int nk, int b, float* __restrict__ acc)
{
    float a0[8], a1[8];
#pragma unroll
    for (int j = 0; j < 8; ++j) a0[j] = src[(size_t)j * B_ + b];
    for (int kc = 0; kc < nk; kc += 8) {
        if (kc + 8 < nk) {
#pragma unroll
            for (int j = 0; j < 8; ++j) a1[j] = src[(size_t)(kc + 8 + j) * B_ + b];
        }
        const float* Wr = W6k + (size_t)kc * 6;
#pragma unroll
        for (int j = 0; j < 8; ++j) {
            float av = a0[j];
            acc[0]      = fmaf(av, Wr[j * 6 + 0], acc[0]);
            acc[1]      = fmaf(av, Wr[j * 6 + 1], acc[1]);
            acc[2]      = fmaf(av, Wr[j * 6 + 2], acc[2]);
            acc[3]      = fmaf(av, Wr[j * 6 + 3], acc[3]);
            acc[NH]     = fmaf(av, Wr[j * 6 + 4], acc[NH]);
            acc[NH + 1] = fmaf(av, Wr[j * 6 + 5], acc[NH + 1]);
        }
#pragma unroll
        for (int j = 0; j < 8; ++j) a0[j] = a1[j];
    }
}

// Wave-0 waits until min over all 256 block slots >= target (own-slot epochs,
// no atomic contention). Caller must __syncthreads() after.
__device__ __forceinline__ void wait_all_blocks(const int* __restrict__ flags,
                                                int tid, int target)
{
    if (tid < 64) {
        while (true) {
            int mn = 0x7fffffff;
#pragma unroll
            for (int q = 0; q < 4; ++q) {
                int vq = __hip_atomic_load(&flags[(tid + q * 64) * 32],
                                           __ATOMIC_RELAXED,
                                           __HIP_MEMORY_SCOPE_AGENT);
                mn = vq < mn ? vq : mn;
            }
            if (__all(mn >= target)) break;
            __builtin_amdgcn_s_sleep(2);
        }
    }
}

// ---------------------------------------------------------------------------
// PERSISTENT encoder: 256 blocks (unit-pair each), 512 threads.
// Publish h rows via sc1 stores; own-slot epoch flags; min-poll wait.
// ---------------------------------------------------------------------------
__global__ __launch_bounds__(512)
void enc_persist(const float* __restrict__ xT,     // [S][F][B]
                 const float* __restrict__ W6,     // [256][640][6]
                 const float* __restrict__ bias4,  // [512][4]
                 const float* __restrict__ h0T,    // [H][B] zeros
                 float* __restrict__ encT,         // [S][H][B]
                 int* __restrict__ eflags)         // [256*32]
{
    __shared__ float accL[256][6];
    const int tid = threadIdx.x;
    const int lane = tid & 63;
    const int w = tid >> 6;
    const int bg = w & 3;
    const int kw = w >> 2;
    const int b = bg * 64 + lane;
    const int up = blockIdx.x;
    const float* Wb = W6 + (size_t)up * (640 * 6);
    const int u0 = up * 2, u1 = u0 + 1;
    const float4 bb0 = *(const float4*)(bias4 + u0 * 4);
    const float4 bb1 = *(const float4*)(bias4 + u1 * 4);

    for (int t = 0; t < S_; ++t) {
        const float* inT = xT + (size_t)t * (F_ * B_);
        const float* hinT = (t == 0) ? h0T : encT + (size_t)(t - 1) * (H_ * B_);
        float* houtT = encT + (size_t)t * (H_ * B_);

        float acc[8];
#pragma unroll
        for (int g = 0; g < 8; ++g) acc[g] = 0.f;

        // x-part first (independent of h) to hide the wait
        if (kw == 0) acc_range<4>(inT, Wb, F_, b, acc);

        if (t > 0) wait_all_blocks(eflags, tid, t);
        __syncthreads();

        if (kw == 0) {
            acc_range<6>(hinT, Wb + F_ * 6, 192, b, acc);
        } else {
            acc_range<6>(hinT + (size_t)192 * B_, Wb + 320 * 6, 320, b, acc);
        }

        if (kw == 1) {
            const int li = tid & 255;
            accL[li][0] = acc[0]; accL[li][1] = acc[1];
            accL[li][2] = acc[2]; accL[li][3] = acc[3];
            accL[li][4] = acc[6]; accL[li][5] = acc[7];
        }
        __syncthreads();
        if (kw == 0) {
            float rr0 = 1.f / (1.f + expf(-(acc[0] + accL[tid][0] + bb0.x)));
            float rr1 = 1.f / (1.f + expf(-(acc[1] + accL[tid][1] + bb1.x)));
            float zz0 = 1.f / (1.f + expf(-(acc[2] + accL[tid][2] + bb0.y)));
            float zz1 = 1.f / (1.f + expf(-(acc[3] + accL[tid][3] + bb1.y)));
            float hn0 = acc[6] + accL[tid][4] + bb0.w;
            float hn1 = acc[7] + accL[tid][5] + bb1.w;
            float nn0 = tanhf(acc[4] + bb0.z + rr0 * hn0);
            float nn1 = tanhf(acc[5] + bb1.z + rr1 * hn1);
            float ho0 = hinT[(size_t)u0 * B_ + b];
            float ho1 = hinT[(size_t)u1 * B_ + b];
            float h0v = (1.f - zz0) * nn0 + zz0 * ho0;
            float h1v = (1.f - zz1) * nn1 + zz1 * ho1;
            __hip_atomic_store(&houtT[(size_t)u0 * B_ + b], h0v,
                               __ATOMIC_RELAXED, __HIP_MEMORY_SCOPE_AGENT);
            __hip_atomic_store(&houtT[(size_t)u1 * B_ + b], h1v,
                               __ATOMIC_RELAXED, __HIP_MEMORY_SCOPE_AGENT);
        }
        asm volatile("s_waitcnt vmcnt(0)" ::: "memory");
        __syncthreads();
        if (tid == 0) {
            __hip_atomic_store(&eflags[up * 32], t + 1,
                               __ATOMIC_RELAXED, __HIP_MEMORY_SCOPE_AGENT);
        }
    }
}

// ---------------------------------------------------------------------------
// FUSED decoder step: phase 1 block=unit-pair GRU (publish hB via sc1 + epoch),
// in-kernel wait, phase 2 block=batch element (w2, scores, softmax, argmax,
// loss, gather). One launch per step.
// ---------------------------------------------------------------------------
__global__ __launch_bounds__(512)
void dec_fused(const float* __restrict__ dec_in,  // [F][B] k-major (in-place)
               const float* __restrict__ hinT,    // [H][B]
               const float* __restrict__ W6,      // [256][640][6]
               const float* __restrict__ bias4,   // [512][4]
               float* __restrict__ houtT,         // [H][B]
               float* __restrict__ hB,            // [B][H]
               const float4* __restrict__ w2q,    // [128 k4][512 a]
               const float* __restrict__ v, const int* __restrict__ y,
               int step, const float* __restrict__ x,
               const float* __restrict__ proj,    // [b][s][a]
               float* __restrict__ dec_out,       // [F][B] (same buffer)
               float* __restrict__ nlogp, float* __restrict__ preds_out,
               int* __restrict__ dflags)          // [256*32]
{
    __shared__ float accL[256][6];
    __shared__ float sh[512];
    __shared__ float sq[512];
    __shared__ float sScore[S_], sProb[S_];
    __shared__ int sPred;

    const int tid = threadIdx.x;
    const int lane = tid & 63;
    const int w = tid >> 6;
    const int bg = w & 3;
    const int kw = w >> 2;
    const int b = bg * 64 + lane;
    const int up = blockIdx.x;

    // ================= phase 1: GRU (block = unit-pair) =================
    {
        const float* Wb = W6 + (size_t)up * (640 * 6);
        float acc[8];
#pragma unroll
        for (int g = 0; g < 8; ++g) acc[g] = 0.f;

        if (kw == 0) {
            acc_range<4>(dec_in, Wb, F_, b, acc);
            acc_range<6>(hinT, Wb + F_ * 6, 192, b, acc);
        } else {
            acc_range<6>(hinT + (size_t)192 * B_, Wb + 320 * 6, 320, b, acc);
        }

        if (kw == 1) {
            const int li = tid & 255;
            accL[li][0] = acc[0]; accL[li][1] = acc[1];
            accL[li][2] = acc[2]; accL[li][3] = acc[3];
            accL[li][4] = acc[6]; accL[li][5] = acc[7];
        }
        __syncthreads();
        if (kw == 0) {
            const int u0 = up * 2, u1 = u0 + 1;
            float4 bb0 = *(const float4*)(bias4 + u0 * 4);
            float4 bb1 = *(const float4*)(bias4 + u1 * 4);
            float rr0 = 1.f / (1.f + expf(-(acc[0] + accL[tid][0] + bb0.x)));
            float rr1 = 1.f / (1.f + expf(-(acc[1] + accL[tid][1] + bb1.x)));
            float zz0 = 1.f / (1.f + expf(-(acc[2] + accL[tid][2] + bb0.y)));
            float zz1 = 1.f / (1.f + expf(-(acc[3] + accL[tid][3] + bb1.y)));
            float hn0 = acc[6] + accL[tid][4] + bb0.w;
            float hn1 = acc[7] + accL[tid][5] + bb1.w;
            float nn0 = tanhf(acc[4] + bb0.z + rr0 * hn0);
            float nn1 = tanhf(acc[5] + bb1.z + rr1 * hn1);
            float ho0 = hinT[(size_t)u0 * B_ + b];
            float ho1 = hinT[(size_t)u1 * B_ + b];
            float h0v = (1.f - zz0) * nn0 + zz0 * ho0;
            float h1v = (1.f - zz1) * nn1 + zz1 * ho1;
            houtT[(size_t)u0 * B_ + b] = h0v;   // next launch only
            houtT[(size_t)u1 * B_ + b] = h1v;
            __hip_atomic_store(&hB[(size_t)b * H_ + u0], h0v,
                               __ATOMIC_RELAXED, __HIP_MEMORY_SCOPE_AGENT);
            __hip_atomic_store(&hB[(size_t)b * H_ + u1], h1v,
                               __ATOMIC_RELAXED, __HIP_MEMORY_SCOPE_AGENT);
        }
        asm volatile("s_waitcnt vmcnt(0)" ::: "memory");
        __syncthreads();
        if (tid == 0) {
            __hip_atomic_store(&dflags[up * 32], step + 1,
                               __ATOMIC_RELAXED, __HIP_MEMORY_SCOPE_AGENT);
        }
    }

    // ================= wait for all phase-1 publishes =================
    wait_all_blocks(dflags, tid, step + 1);
    __syncthreads();

    // ================= phase 2: attention (block = batch bb) =================
    const int bb = blockIdx.x;
    // hB lines mix 16 writer blocks -> read with sc1 (cache-bypassing) loads
    sh[tid] = __hip_atomic_load(&hB[(size_t)bb * H_ + tid],
                                __ATOMIC_RELAXED, __HIP_MEMORY_SCOPE_AGENT);
    __syncthreads();

    {
        float acc = 0.f;
        const float4* wp = w2q + tid;
#pragma unroll 8
        for (int k4 = 0; k4 < 128; ++k4) {
            float4 hv = *(const float4*)&sh[k4 * 4];
            float4 wv4 = wp[(size_t)k4 * 512];
            acc += DOT4(hv, wv4);
        }
        sq[tid] = acc;
    }
    __syncthreads();

    const int wv = tid >> 6, ln = tid & 63;
    float4 q0 = *(const float4*)&sq[ln * 8];
    float4 q1 = *(const float4*)&sq[ln * 8 + 4];
    float4 v0r = *(const float4*)(v + ln * 8);
    float4 v1r = *(const float4*)(v + ln * 8 + 4);
    const float* epb = proj + (size_t)bb * (S_ * A_);
    for (int si = 0; si < 16; ++si) {
        int s = si * 8 + wv;
        const float* row = epb + (size_t)s * A_ + ln * 8;
        float4 p0 = *(const float4*)(row);
        float4 p1 = *(const float4*)(row + 4);
        float acc = fmaxf(p0.x + q0.x, 0.f) * v0r.x
                  + fmaxf(p0.y + q0.y, 0.f) * v0r.y
                  + fmaxf(p0.z + q0.z, 0.f) * v0r.z
                  + fmaxf(p0.w + q0.w, 0.f) * v0r.w
                  + fmaxf(p1.x + q1.x, 0.f) * v1r.x
                  + fmaxf(p1.y + q1.y, 0.f) * v1r.y
                  + fmaxf(p1.z + q1.z, 0.f) * v1r.z
                  + fmaxf(p1.w + q1.w, 0.f) * v1r.w;
#pragma unroll
        for (int off = 32; off; off >>= 1) acc += __shfl_down(acc, off);
        if (ln == 0) sScore[s] = acc;
    }
    __syncthreads();

    if (tid < 64) {
        float s0v = sScore[tid], s1v = sScore[tid + 64];
        float m = fmaxf(s0v, s1v);
#pragma unroll
        for (int off = 32; off; off >>= 1) m = fmaxf(m, __shfl_xor(m, off));
        float e0 = expf(s0v - m), e1 = expf(s1v - m);
        float se = e0 + e1;
#pragma unroll
        for (int off = 32; off; off >>= 1) se += __shfl_xor(se, off);
        float p0 = e0 / se, p1 = e1 / se;
        sProb[tid] = p0; sProb[tid + 64] = p1;
        float pm = fmaxf(p0, p1);
#pragma unroll
        for (int off = 32; off; off >>= 1) pm = fmaxf(pm, __shfl_xor(pm, off));
        float t0 = expf(p0 - pm), t1 = expf(p1 - pm);
        float T = t0 + t1;
#pragma unroll
        for (int off = 32; off; off >>= 1) T += __shfl_xor(T, off);
        float bv = p0; int bi2 = tid;
        if (p1 > bv) { bv = p1; bi2 = tid + 64; }
#pragma unroll
        for (int off = 32; off; off >>= 1) {
            float ov = __shfl_xor(bv, off);
            int oi = __shfl_xor(bi2, off);
            if (ov > bv || (ov == bv && oi < bi2)) { bv = ov; bi2 = oi; }
        }
        if (tid == 0) {
            sPred = bi2;
            int yy = y[(size_t)bb * C_ + step];
            float py = sProb[yy];
            nlogp[(size_t)step * B_ + bb] = -(py - pm - logf(T));
            preds_out[(size_t)bb * C_ + step] = (float)bi2;
        }
    }
    __syncthreads();

    const int pred = sPred;
    if (tid < F_) {
        dec_out[(size_t)tid * B_ + bb] = x[((size_t)bb * S_ + pred) * F_ + tid];
    }
}

// ---------------------------------------------------------------------------
// proj[b][s][a] = sum_j encT[s][j][b] * w1[a][j]   (TN GEMM, 128x128 tiles)
// ---------------------------------------------------------------------------
__global__ __launch_bounds__(256)
void proj_gemm(const float* __restrict__ encT, const float* __restrict__ w1,
               float* __restrict__ proj)
{
    __shared__ float sA[32][128];
    __shared__ float sB[32][128];
    const int tid = threadIdx.x;
    const int s = blockIdx.z;
    const int b0 = blockIdx.y * 128;
    const int a0 = blockIdx.x * 128;
    const int tx = tid & 15, ty = tid >> 4;

    float acc[8][8];
#pragma unroll
    for (int i = 0; i < 8; ++i)
#pragma unroll
        for (int j = 0; j < 8; ++j) acc[i][j] = 0.f;

    const float* Abase = encT + (size_t)s * (H_ * B_) + b0;
    for (int kc = 0; kc < H_; kc += 32) {
#pragma unroll
        for (int p = 0; p < 16; ++p) {
            int idx = tid + p * 256;
            int kj = idx >> 7, bbb = idx & 127;
            sA[kj][bbb] = Abase[(size_t)(kc + kj) * B_ + bbb];
        }
#pragma unroll
        for (int p = 0; p < 16; ++p) {
            int idx = tid + p * 256;
            int aa = idx >> 5, kj = idx & 31;
            sB[kj][aa] = w1[(size_t)(a0 + aa) * H_ + kc + kj];
        }
        __syncthreads();
#pragma unroll
        for (int kj = 0; kj < 32; ++kj) {
            float4 af0 = *(const float4*)&sA[kj][ty * 8];
            float4 af1 = *(const float4*)&sA[kj][ty * 8 + 4];
            float4 bf0 = *(const float4*)&sB[kj][tx * 8];
            float4 bf1 = *(const float4*)&sB[kj][tx * 8 + 4];
            float am[8] = {af0.x, af0.y, af0.z, af0.w, af1.x, af1.y, af1.z, af1.w};
            float bn[8] = {bf0.x, bf0.y, bf0.z, bf0.w, bf1.x, bf1.y, bf1.z, bf1.w};
#pragma unroll
            for (int i = 0; i < 8; ++i)
#pragma unroll
                for (int j = 0; j < 8; ++j)
                    acc[i][j] = fmaf(am[i], bn[j], acc[i][j]);
        }
        __syncthreads();
    }
#pragma unroll
    for (int i = 0; i < 8; ++i) {
        float* dst = proj + ((size_t)(b0 + ty * 8 + i) * S_ + s) * A_ + a0 + tx * 8;
        *(float4*)(dst) = make_float4(acc[i][0], acc[i][1], acc[i][2], acc[i][3]);
        *(float4*)(dst + 4) = make_float4(acc[i][4], acc[i][5], acc[i][6], acc[i][7]);
    }
}

__global__ void final_loss(const float* __restrict__ nlogp, float* __restrict__ out)
{
    __shared__ float part[C_];
    const int i = threadIdx.x; // 128
    float s = 0.f;
    for (int b = 0; b < B_; ++b) s += nlogp[(size_t)i * B_ + b];
    part[i] = s / (float)B_;
    __syncthreads();
    if (i == 0) {
        float t = 0.f;
        for (int k = 0; k < C_; ++k) t += part[k];
        out[0] = t / (float)B_ / (float)C_;
    }
}

extern "C" void kernel_launch(void* const* d_in, const int* in_sizes, int n_in,
                              void* d_out, int out_size, void* d_ws, size_t ws_size,
                              hipStream_t stream)
{
    (void)in_sizes; (void)n_in; (void)out_size; (void)ws_size;
    const float* x    = (const float*)d_in[0];
    const int*   y    = (const int*)d_in[1];
    const float* eWih = (const float*)d_in[2];
    const float* eWhh = (const float*)d_in[3];
    const float* ebih = (const float*)d_in[4];
    const float* ebhh = (const float*)d_in[5];
    const float* dWih = (const float*)d_in[6];
    const float* dWhh = (const float*)d_in[7];
    const float* dbih = (const float*)d_in[8];
    const float* dbhh = (const float*)d_in[9];
    const float* w1   = (const float*)d_in[10];
    const float* w2   = (const float*)d_in[11];
    const float* v    = (const float*)d_in[12];
    float* out = (float*)d_out;

    float* ws = (float*)d_ws;
    // Region A: encT [128][512][256] = 16,777,216 floats.
    float* encT    = ws;
    float* W6d     = ws;                    // 983,040 (dead encT slices)
    float* w2qf    = ws + 983040;           // 262,144
    float* hT0     = ws + 1245184;          // 131,072
    float* hT1     = ws + 1376256;          // 131,072
    float* dec_inT = ws + 1507328;          // 32,768
    float* nlogp   = ws + 1540096;          // 32,768
    float* hB      = ws + 1572864;          // 131,072
    float* encT127 = ws + 16646144;         // encoder final h (stays live)
    // Region B: proj. Before proj written: xT, W6e, h0T.
    float* projB   = ws + 16777216;
    float* xT      = projB;                 // 4,194,304
    float* W6e     = projB + 4194304;       // 983,040
    float* h0T     = projB + 5177344;       // 131,072
    // Region C
    float* bias4e  = ws + 33554432;
    float* bias4d  = bias4e + 2048;
    int*   eflags  = (int*)(bias4d + 2048);   // 256*32 ints
    int*   dflags  = eflags + 256 * 32;       // 256*32 ints

    // ---- prep ----
    prep_bias<<<dim3(512), 256, 0, stream>>>(ebih, ebhh, dbih, dbhh,
                                             bias4e, bias4d, h0T, eflags, dflags);
    transpose_x<<<dim3(512), 256, 0, stream>>>(x, xT);
    prep_w6<<<dim3(3840), 256, 0, stream>>>(eWih, eWhh, W6e);

    // ---- encoder: ONE persistent kernel ----
    {
        void* a[] = { (void*)&xT, (void*)&W6e, (void*)&bias4e, (void*)&h0T,
                      (void*)&encT, (void*)&eflags };
        hipLaunchCooperativeKernel((const void*)enc_persist,
                                   dim3(256), dim3(512), a, 0, stream);
    }

    // ---- proj ----
    proj_gemm<<<dim3(4, 2, 128), 256, 0, stream>>>(encT, w1, projB);

    // ---- decoder prep (into dead encT slices; after proj_gemm read) ----
    prep_w6<<<dim3(3840), 256, 0, stream>>>(dWih, dWhh, W6d);
    prep_w2q<<<dim3(256), 256, 0, stream>>>(w2, (float4*)w2qf, dec_inT);

    // ---- decoder: 128 fused steps ----
    float* hb[2] = { hT0, hT1 };
    for (int i = 0; i < C_; ++i) {
        const float* hin = (i == 0) ? encT127 : hb[(i & 1) ^ 1];
        float* hout = hb[i & 1];
        dec_fused<<<dim3(256), 512, 0, stream>>>(
            dec_inT, hin, W6d, bias4d, hout, hB, (const float4*)w2qf, v, y,
            i, x, projB, dec_inT, nlogp, out, dflags);
    }

    final_loss<<<dim3(1), 128, 0, stream>>>(nlogp, out + (size_t)B_ * C_);
}